// Round 11
// baseline (226.520 us; speedup 1.0000x reference)
//
#include <hip/hip_runtime.h>
#include <hip/hip_cooperative_groups.h>
#include <stdint.h>

namespace cg = cooperative_groups;

typedef float  floatx4 __attribute__((ext_vector_type(4)));
typedef short  short8  __attribute__((ext_vector_type(8)));
typedef float  f4v     __attribute__((ext_vector_type(4)));
typedef unsigned int uint32;

#define GS_EPS 1e-10f

__device__ __forceinline__ unsigned short f2bf(float x) {
  uint32 u = __float_as_uint(x);
  u += 0x7FFFu + ((u >> 16) & 1u);
  return (unsigned short)(u >> 16);
}
// sign-extend byte j (0..3) of w, to float
__device__ __forceinline__ float i8tof(uint32 w, int j) {
  int b = (int)(w << (24 - 8 * j)) >> 24;
  return (float)b;
}
__device__ __forceinline__ uint32 pack4_i8(floatx4 a, float inv) {
  uint32 r = 0;
#pragma unroll
  for (int i = 0; i < 4; ++i) {
    float x = a[i] * inv;
    x = fminf(fmaxf(x, -127.f), 127.f);
    int v = (int)__builtin_rintf(x);
    r |= ((uint32)(v & 255)) << (8 * i);
  }
  return r;
}

// ================= FUSED cooperative kernel =================
// Phase 1: P8[node][128] = int8{ e@W1_top+b1 ; e@W1_bot }, per-64-node-tile
//   top/bot scales -> Sc[tile] (float2). 256 thr = 4 waves x 16 nodes.
//   782 tiles all co-resident in ONE round (vs 2-round tail of the 391x512
//   variant). W1 (64KB, L2-resident) converted to bf16 LDS per block.
// grid.sync()
// Phase 2: edge gathers + dequant dot + gumbel-sigmoid, grid-strided.
//   Sc table staged in LDS (reuses w1blk).
__global__ __launch_bounds__(256, 4) void fused_kernel(
    const float* __restrict__ E, const float* __restrict__ W1,
    const float* __restrict__ b1, const int* __restrict__ ei,
    const float* __restrict__ u1, const float* __restrict__ u2,
    const float* __restrict__ W2, const float* __restrict__ b2,
    uint8_t* __restrict__ P8, float2* __restrict__ Sc,
    float* __restrict__ out, int num_nodes, int num_edges, int ntiles) {
  __shared__ __align__(16) unsigned short w1blk[16 * 128 * 8];  // 32 KB
  __shared__ float wmt[4], wmb[4];

  const int tid = threadIdx.x;
  const int wave = tid >> 6;
  const int lane = tid & 63;
  const int q = lane >> 4;
  const int l16 = lane & 15;

  // ---- stage W1 -> bf16 LDS once (shared by all tiles this block handles)
  // w1blk[(chunk*128+n)*8+kk] = bf16( n<64 ? W1[chunk*8+kk][n] : W1[128+chunk*8+kk][n-64] )
#pragma unroll
  for (int it = 0; it < 8; ++it) {
    int idx = it * 256 + tid;  // 0..2047 = chunk*128 + n
    int chunk = idx >> 7;
    int n = idx & 127;
    const float* src = (n < 64) ? (W1 + n) : (W1 + 128 * 64 + (n - 64));
    uint32 d[4];
#pragma unroll
    for (int j = 0; j < 4; ++j) {
      int k0 = chunk * 8 + 2 * j;
      unsigned short lo = f2bf(src[(size_t)k0 * 64]);
      unsigned short hi = f2bf(src[(size_t)(k0 + 1) * 64]);
      d[j] = (uint32)lo | ((uint32)hi << 16);
    }
#pragma unroll
    for (int j = 0; j < 4; ++j) *(uint32*)&w1blk[(size_t)idx * 8 + 2 * j] = d[j];
  }
  __syncthreads();

  // ---- phase 1: per-tile (64 nodes) MFMA + quantize
  for (int t0 = blockIdx.x; t0 < ntiles; t0 += gridDim.x) {
    const int rowbase = t0 * 64 + wave * 16;
    int row = rowbase + l16;
    const bool ok = row < num_nodes;
    if (!ok) row = num_nodes - 1;

    short8 bfr[4];
#pragma unroll
    for (int kk = 0; kk < 4; ++kk) {
      const float* p = E + (size_t)row * 128 + kk * 32 + q * 8;
      f4v v0 = *(const f4v*)p;
      f4v v1 = *(const f4v*)(p + 4);
      short8 t;
      t[0] = (short)f2bf(v0[0]); t[1] = (short)f2bf(v0[1]);
      t[2] = (short)f2bf(v0[2]); t[3] = (short)f2bf(v0[3]);
      t[4] = (short)f2bf(v1[0]); t[5] = (short)f2bf(v1[1]);
      t[6] = (short)f2bf(v1[2]); t[7] = (short)f2bf(v1[3]);
      bfr[kk] = t;
    }

    floatx4 acc[8];
#pragma unroll
    for (int t = 0; t < 8; ++t) {
      floatx4 z = {0.f, 0.f, 0.f, 0.f};
      acc[t] = z;
    }
#pragma unroll
    for (int kk = 0; kk < 4; ++kk) {
#pragma unroll
      for (int t = 0; t < 8; ++t) {
        short8 af = *(const short8*)&w1blk[(size_t)((kk * 4 + q) * 128 + t * 16 + l16) * 8];
        acc[t] = __builtin_amdgcn_mfma_f32_16x16x32_bf16(af, bfr[kk], acc[t], 0, 0, 0);
      }
    }

    // fold b1 into top half (j<64 <=> t<4); per-lane half absmax
    float mtop = 0.f, mbot = 0.f;
#pragma unroll
    for (int t = 0; t < 8; ++t) {
      floatx4 a = acc[t];
      if (t < 4) {
        f4v bv = *(const f4v*)(b1 + t * 16 + q * 4);
        a[0] += bv[0]; a[1] += bv[1]; a[2] += bv[2]; a[3] += bv[3];
        acc[t] = a;
      }
      float m = fmaxf(fmaxf(fabsf(a[0]), fabsf(a[1])), fmaxf(fabsf(a[2]), fabsf(a[3])));
      if (t < 4) mtop = fmaxf(mtop, m); else mbot = fmaxf(mbot, m);
    }
#pragma unroll
    for (int s = 1; s < 64; s <<= 1) {
      mtop = fmaxf(mtop, __shfl_xor(mtop, s, 64));
      mbot = fmaxf(mbot, __shfl_xor(mbot, s, 64));
    }
    if (lane == 0) {
      wmt[wave] = mtop;
      wmb[wave] = mbot;
    }
    __syncthreads();
    float bt = fmaxf(fmaxf(wmt[0], wmt[1]), fmaxf(wmt[2], wmt[3]));
    float bb = fmaxf(fmaxf(wmb[0], wmb[1]), fmaxf(wmb[2], wmb[3]));
    const float invt = 127.f / fmaxf(bt, 1e-20f);
    const float invb = 127.f / fmaxf(bb, 1e-20f);

    if (ok) {
      const int node = rowbase + l16;
#pragma unroll
      for (int t = 0; t < 8; ++t) {
        *(uint32*)(P8 + (size_t)node * 128 + t * 16 + q * 4) =
            pack4_i8(acc[t], (t < 4) ? invt : invb);
      }
    }
    if (tid == 0)
      Sc[t0] = make_float2(bt * (1.f / 127.f), bb * (1.f / 127.f));
    __syncthreads();  // wmt/wmb reuse next tile
  }

  __threadfence();
  cg::this_grid().sync();

  // ---- phase 2: stage Sc (ntiles x 8B, ~6.3 KB) into LDS, then edges
  float2* scs = (float2*)w1blk;
  for (int i = tid; i < ntiles; i += 256) scs[i] = Sc[i];
  __syncthreads();

  const int g = lane >> 2;  // edge-within-slot (0..15)
  const int h = lane & 3;   // lane-within-edge (0..3)
  f4v w0 = *(const f4v*)(W2 + h * 16);
  f4v w1v = *(const f4v*)(W2 + h * 16 + 4);
  f4v w2v = *(const f4v*)(W2 + h * 16 + 8);
  f4v w3v = *(const f4v*)(W2 + h * 16 + 12);
  const float bias2 = b2[0];

  for (int base = blockIdx.x * 128; base < num_edges; base += gridDim.x * 128) {
    const int wbase = base + wave * 32;
    if (wbase >= num_edges) continue;  // per-wave uniform

    int el = wbase + (lane & 31);
    if (el > num_edges - 1) el = num_edges - 1;
    // int64-vs-int32 detection (per-wave uniform): int64 LE => odd words all 0
    unsigned long long oddmask = __ballot(ei[2 * el + 1] != 0);
    const bool idx64 = (oddmask == 0ULL);
    int eR, eC;
    if (idx64) {
      eR = ei[2 * el];
      eC = ei[2 * (num_edges + el)];
    } else {
      eR = ei[el];
      eC = ei[num_edges + el];
    }

    uint4 ar[2], ac[2];
    float srv[2], scv[2];
#pragma unroll
    for (int s = 0; s < 2; ++s) {
      int nr = __shfl(eR, s * 16 + g, 64);
      int nc = __shfl(eC, s * 16 + g, 64);
      ar[s] = *(const uint4*)(P8 + (size_t)nr * 128 + h * 16);
      ac[s] = *(const uint4*)(P8 + (size_t)nc * 128 + 64 + h * 16);
      srv[s] = scs[nr >> 6].x;  // top-half scale of row node's tile
      scv[s] = scs[nc >> 6].y;  // bot-half scale of col node's tile
    }

#pragma unroll
    for (int s = 0; s < 2; ++s) {
      float accv = 0.f;
      const float st = srv[s], sb = scv[s];
      const uint32 rw[4] = {ar[s].x, ar[s].y, ar[s].z, ar[s].w};
      const uint32 cw[4] = {ac[s].x, ac[s].y, ac[s].z, ac[s].w};
      const f4v wv[4] = {w0, w1v, w2v, w3v};
#pragma unroll
      for (int wi = 0; wi < 4; ++wi) {
#pragma unroll
        for (int j = 0; j < 4; ++j) {
          float hv = fmaxf(i8tof(rw[wi], j) * st + i8tof(cw[wi], j) * sb, 0.f);
          accv = fmaf(hv, wv[wi][j], accv);
        }
      }
      accv += __shfl_xor(accv, 1, 64);
      accv += __shfl_xor(accv, 2, 64);
      if (h == 0) {
        int e = wbase + s * 16 + g;
        if (e < num_edges) {
          float a1 = fminf(fmaxf(u1[e], GS_EPS), 1.0f);
          float a2 = fminf(fmaxf(u2[e], GS_EPS), 1.0f);
          float g1 = -__logf(-__logf(a1));
          float g2 = -__logf(-__logf(a2));
          float x = accv + bias2 + g1 - g2;  // TEMP = 1.0
          out[e] = 1.f / (1.f + __expf(-x));
        }
      }
    }
  }
}

// ================= Fallback path (proven R5 kernels, verbatim) =================
__global__ __launch_bounds__(512, 4) void pcompute_kernel(
    const float* __restrict__ E, const float* __restrict__ W1,
    const float* __restrict__ b1, uint8_t* __restrict__ P8,
    float2* __restrict__ Sc, int num_nodes) {
  __shared__ __align__(16) unsigned short w1blk[16 * 128 * 8];
  __shared__ float wmt[8], wmb[8];

  const int tid = threadIdx.x;
  const int wave = tid >> 6;
  const int lane = tid & 63;
  const int q = lane >> 4;
  const int l16 = lane & 15;

#pragma unroll
  for (int it = 0; it < 4; ++it) {
    int idx = it * 512 + tid;
    int chunk = idx >> 7;
    int n = idx & 127;
    const float* src = (n < 64) ? (W1 + n) : (W1 + 128 * 64 + (n - 64));
    uint32 d[4];
#pragma unroll
    for (int j = 0; j < 4; ++j) {
      int k0 = chunk * 8 + 2 * j;
      unsigned short lo = f2bf(src[(size_t)k0 * 64]);
      unsigned short hi = f2bf(src[(size_t)(k0 + 1) * 64]);
      d[j] = (uint32)lo | ((uint32)hi << 16);
    }
#pragma unroll
    for (int j = 0; j < 4; ++j) *(uint32*)&w1blk[(size_t)idx * 8 + 2 * j] = d[j];
  }

  const int rowbase = blockIdx.x * 128 + wave * 16;
  int row = rowbase + l16;
  const bool ok = row < num_nodes;
  if (!ok) row = num_nodes - 1;

  short8 bfr[4];
#pragma unroll
  for (int kk = 0; kk < 4; ++kk) {
    const float* p = E + (size_t)row * 128 + kk * 32 + q * 8;
    f4v v0 = *(const f4v*)p;
    f4v v1 = *(const f4v*)(p + 4);
    short8 t;
    t[0] = (short)f2bf(v0[0]); t[1] = (short)f2bf(v0[1]);
    t[2] = (short)f2bf(v0[2]); t[3] = (short)f2bf(v0[3]);
    t[4] = (short)f2bf(v1[0]); t[5] = (short)f2bf(v1[1]);
    t[6] = (short)f2bf(v1[2]); t[7] = (short)f2bf(v1[3]);
    bfr[kk] = t;
  }
  __syncthreads();

  floatx4 acc[8];
#pragma unroll
  for (int t = 0; t < 8; ++t) {
    floatx4 z = {0.f, 0.f, 0.f, 0.f};
    acc[t] = z;
  }
#pragma unroll
  for (int kk = 0; kk < 4; ++kk) {
#pragma unroll
    for (int t = 0; t < 8; ++t) {
      short8 af = *(const short8*)&w1blk[(size_t)((kk * 4 + q) * 128 + t * 16 + l16) * 8];
      acc[t] = __builtin_amdgcn_mfma_f32_16x16x32_bf16(af, bfr[kk], acc[t], 0, 0, 0);
    }
  }

  float mtop = 0.f, mbot = 0.f;
#pragma unroll
  for (int t = 0; t < 8; ++t) {
    floatx4 a = acc[t];
    if (t < 4) {
      f4v bv = *(const f4v*)(b1 + t * 16 + q * 4);
      a[0] += bv[0]; a[1] += bv[1]; a[2] += bv[2]; a[3] += bv[3];
      acc[t] = a;
    }
    float m = fmaxf(fmaxf(fabsf(a[0]), fabsf(a[1])), fmaxf(fabsf(a[2]), fabsf(a[3])));
    if (t < 4) mtop = fmaxf(mtop, m); else mbot = fmaxf(mbot, m);
  }
#pragma unroll
  for (int s = 1; s < 64; s <<= 1) {
    mtop = fmaxf(mtop, __shfl_xor(mtop, s, 64));
    mbot = fmaxf(mbot, __shfl_xor(mbot, s, 64));
  }
  if (lane == 0) {
    wmt[wave] = mtop;
    wmb[wave] = mbot;
  }
  __syncthreads();
  float bt = wmt[0], bb = wmb[0];
#pragma unroll
  for (int i = 1; i < 8; ++i) {
    bt = fmaxf(bt, wmt[i]);
    bb = fmaxf(bb, wmb[i]);
  }
  const float invt = 127.f / fmaxf(bt, 1e-20f);
  const float invb = 127.f / fmaxf(bb, 1e-20f);

  if (ok) {
    const int node = rowbase + l16;
#pragma unroll
    for (int t = 0; t < 8; ++t) {
      *(uint32*)(P8 + (size_t)node * 128 + t * 16 + q * 4) =
          pack4_i8(acc[t], (t < 4) ? invt : invb);
    }
  }
  if (tid == 0)
    Sc[blockIdx.x] = make_float2(bt * (1.f / 127.f), bb * (1.f / 127.f));
}

__global__ __launch_bounds__(256, 8) void edge_kernel(
    const uint8_t* __restrict__ P8, const float2* __restrict__ Sc,
    const int* __restrict__ ei,
    const float* __restrict__ u1, const float* __restrict__ u2,
    const float* __restrict__ W2, const float* __restrict__ b2,
    float* __restrict__ out, int num_edges, int nsc) {
  __shared__ float2 scs[2048];
  const int tid = threadIdx.x;
  const bool useLds = (nsc <= 2048);
  if (useLds) {
    for (int i = tid; i < nsc; i += 256) scs[i] = Sc[i];
  }

  const int wave = tid >> 6;
  const int lane = tid & 63;
  const int g = lane >> 2;
  const int h = lane & 3;
  const int wbase = blockIdx.x * 128 + wave * 32;

  f4v w0 = *(const f4v*)(W2 + h * 16);
  f4v w1v = *(const f4v*)(W2 + h * 16 + 4);
  f4v w2v = *(const f4v*)(W2 + h * 16 + 8);
  f4v w3v = *(const f4v*)(W2 + h * 16 + 12);
  const float bias2 = b2[0];

  int el = wbase + (lane & 31);
  if (el > num_edges - 1) el = num_edges - 1;
  unsigned long long oddmask = __ballot(ei[2 * el + 1] != 0);
  const bool idx64 = (oddmask == 0ULL);
  int eR, eC;
  if (idx64) {
    eR = ei[2 * el];
    eC = ei[2 * (num_edges + el)];
  } else {
    eR = ei[el];
    eC = ei[num_edges + el];
  }

  __syncthreads();

  uint4 ar[2], ac[2];
  float srv[2], scv[2];
#pragma unroll
  for (int s = 0; s < 2; ++s) {
    int nr = __shfl(eR, s * 16 + g, 64);
    int nc = __shfl(eC, s * 16 + g, 64);
    ar[s] = *(const uint4*)(P8 + (size_t)nr * 128 + h * 16);
    ac[s] = *(const uint4*)(P8 + (size_t)nc * 128 + 64 + h * 16);
    if (useLds) {
      srv[s] = scs[nr >> 7].x;
      scv[s] = scs[nc >> 7].y;
    } else {
      srv[s] = Sc[nr >> 7].x;
      scv[s] = Sc[nc >> 7].y;
    }
  }

#pragma unroll
  for (int s = 0; s < 2; ++s) {
    float accv = 0.f;
    const float st = srv[s], sb = scv[s];
    const uint32 rw[4] = {ar[s].x, ar[s].y, ar[s].z, ar[s].w};
    const uint32 cw[4] = {ac[s].x, ac[s].y, ac[s].z, ac[s].w};
    const f4v wv[4] = {w0, w1v, w2v, w3v};
#pragma unroll
    for (int wi = 0; wi < 4; ++wi) {
#pragma unroll
      for (int j = 0; j < 4; ++j) {
        float hv = fmaxf(i8tof(rw[wi], j) * st + i8tof(cw[wi], j) * sb, 0.f);
        accv = fmaf(hv, wv[wi][j], accv);
      }
    }
    accv += __shfl_xor(accv, 1, 64);
    accv += __shfl_xor(accv, 2, 64);
    if (h == 0) {
      int e = wbase + s * 16 + g;
      if (e < num_edges) {
        float a1 = fminf(fmaxf(u1[e], GS_EPS), 1.0f);
        float a2 = fminf(fmaxf(u2[e], GS_EPS), 1.0f);
        float g1 = -__logf(-__logf(a1));
        float g2 = -__logf(-__logf(a2));
        float x = accv + bias2 + g1 - g2;
        out[e] = 1.f / (1.f + __expf(-x));
      }
    }
  }
}

extern "C" void kernel_launch(void* const* d_in, const int* in_sizes, int n_in,
                              void* d_out, int out_size, void* d_ws, size_t ws_size,
                              hipStream_t stream) {
  const float* node_embed = (const float*)d_in[0];
  const int* ei = (const int*)d_in[1];
  const float* u1 = (const float*)d_in[2];
  const float* u2 = (const float*)d_in[3];
  const float* W1 = (const float*)d_in[4];
  const float* b1 = (const float*)d_in[5];
  const float* W2 = (const float*)d_in[6];
  const float* b2 = (const float*)d_in[7];
  float* out = (float*)d_out;

  const int num_edges = in_sizes[2];        // u1 length
  const int num_nodes = in_sizes[0] / 128;  // embed_dim = 128
  const int ntiles = (num_nodes + 63) / 64;

  // workspace layout (256B-aligned chunks)
  char* w = (char*)d_ws;
  uint8_t* P8 = (uint8_t*)w;   w += ((size_t)num_nodes * 128 + 255) & ~(size_t)255;
  float2* Sc = (float2*)w;

  // co-residency-safe grid for the cooperative launch
  int maxb = 0;
  hipOccupancyMaxActiveBlocksPerMultiprocessor(&maxb, fused_kernel, 256, 0);
  if (maxb < 1) maxb = 1;
  long long grid = (long long)maxb * 256;  // 256 CUs on MI355X
  if (grid > 1024) grid = 1024;

  void* args[] = {(void*)&node_embed, (void*)&W1, (void*)&b1, (void*)&ei,
                  (void*)&u1, (void*)&u2, (void*)&W2, (void*)&b2,
                  (void*)&P8, (void*)&Sc, (void*)&out,
                  (void*)&num_nodes, (void*)&num_edges, (void*)&ntiles};
  hipError_t err = hipLaunchCooperativeKernel(
      fused_kernel, dim3((uint32_t)grid), dim3(256), args, 0, stream);

  if (err != hipSuccess) {
    // fallback: proven two-kernel path (128-node scale tiles)
    const int pblocks = (num_nodes + 127) / 128;
    pcompute_kernel<<<pblocks, 512, 0, stream>>>(node_embed, W1, b1, P8, Sc, num_nodes);
    const int eblocks = (num_edges + 127) / 128;
    edge_kernel<<<eblocks, 256, 0, stream>>>(P8, Sc, ei, u1, u2, W2, b2, out, num_edges, pblocks);
  }
}

// Round 12
// 110.908 us; speedup vs baseline: 2.0424x; 2.0424x over previous
//
#include <hip/hip_runtime.h>
#include <stdint.h>

typedef float  floatx4 __attribute__((ext_vector_type(4)));
typedef short  short8  __attribute__((ext_vector_type(8)));
typedef float  f4v     __attribute__((ext_vector_type(4)));
typedef unsigned int uint32;

#define GS_EPS 1e-10f

__device__ __forceinline__ unsigned short f2bf(float x) {
  uint32 u = __float_as_uint(x);
  u += 0x7FFFu + ((u >> 16) & 1u);
  return (unsigned short)(u >> 16);
}
// sign-extend byte j (0..3) of w, to float
__device__ __forceinline__ float i8tof(uint32 w, int j) {
  int b = (int)(w << (24 - 8 * j)) >> 24;
  return (float)b;
}
__device__ __forceinline__ uint32 pack4_i8(floatx4 a, float inv) {
  uint32 r = 0;
#pragma unroll
  for (int i = 0; i < 4; ++i) {
    float x = a[i] * inv;
    x = fminf(fmaxf(x, -127.f), 127.f);
    int v = (int)__builtin_rintf(x);
    r |= ((uint32)(v & 255)) << (8 * i);
  }
  return r;
}

// ---- precompute P8[node][128] = int8{ e@W1_top+b1 (64B) ; e@W1_bot (64B) },
// quantized with PER-BLOCK (128 nodes) top/bot scales -> Sc[block] (float2).
// W1 conversion (fp32 [256][64] -> bf16 blocked) folded in-block (R5-proven).
// NOTE R11 lesson: cooperative grid.sync fusion of the two kernels costs
// ~200us on MI355X (1024-block cross-XCD atomic barrier) — keep 2 dispatches.
__global__ __launch_bounds__(512, 4) void pcompute_kernel(
    const float* __restrict__ E, const float* __restrict__ W1,
    const float* __restrict__ b1, uint8_t* __restrict__ P8,
    float2* __restrict__ Sc, int num_nodes) {
  __shared__ __align__(16) unsigned short w1blk[16 * 128 * 8];  // 32 KB
  __shared__ float wmt[8], wmb[8];

  const int tid = threadIdx.x;
  const int wave = tid >> 6;
  const int lane = tid & 63;
  const int q = lane >> 4;
  const int l16 = lane & 15;

#pragma unroll
  for (int it = 0; it < 4; ++it) {
    int idx = it * 512 + tid;  // 0..2047 = chunk*128 + n
    int chunk = idx >> 7;
    int n = idx & 127;
    const float* src = (n < 64) ? (W1 + n) : (W1 + 128 * 64 + (n - 64));
    uint32 d[4];
#pragma unroll
    for (int j = 0; j < 4; ++j) {
      int k0 = chunk * 8 + 2 * j;
      unsigned short lo = f2bf(src[(size_t)k0 * 64]);
      unsigned short hi = f2bf(src[(size_t)(k0 + 1) * 64]);
      d[j] = (uint32)lo | ((uint32)hi << 16);
    }
#pragma unroll
    for (int j = 0; j < 4; ++j) *(uint32*)&w1blk[(size_t)idx * 8 + 2 * j] = d[j];
  }

  const int rowbase = blockIdx.x * 128 + wave * 16;
  int row = rowbase + l16;
  const bool ok = row < num_nodes;
  if (!ok) row = num_nodes - 1;

  short8 bfr[4];
#pragma unroll
  for (int kk = 0; kk < 4; ++kk) {
    const float* p = E + (size_t)row * 128 + kk * 32 + q * 8;
    f4v v0 = *(const f4v*)p;
    f4v v1 = *(const f4v*)(p + 4);
    short8 t;
    t[0] = (short)f2bf(v0[0]); t[1] = (short)f2bf(v0[1]);
    t[2] = (short)f2bf(v0[2]); t[3] = (short)f2bf(v0[3]);
    t[4] = (short)f2bf(v1[0]); t[5] = (short)f2bf(v1[1]);
    t[6] = (short)f2bf(v1[2]); t[7] = (short)f2bf(v1[3]);
    bfr[kk] = t;
  }
  __syncthreads();

  floatx4 acc[8];
#pragma unroll
  for (int t = 0; t < 8; ++t) {
    floatx4 z = {0.f, 0.f, 0.f, 0.f};
    acc[t] = z;
  }
#pragma unroll
  for (int kk = 0; kk < 4; ++kk) {
#pragma unroll
    for (int t = 0; t < 8; ++t) {
      short8 af = *(const short8*)&w1blk[(size_t)((kk * 4 + q) * 128 + t * 16 + l16) * 8];
      acc[t] = __builtin_amdgcn_mfma_f32_16x16x32_bf16(af, bfr[kk], acc[t], 0, 0, 0);
    }
  }

  // fold b1 into top half (j<64 <=> t<4); per-lane half absmax
  float mtop = 0.f, mbot = 0.f;
#pragma unroll
  for (int t = 0; t < 8; ++t) {
    floatx4 a = acc[t];
    if (t < 4) {
      f4v bv = *(const f4v*)(b1 + t * 16 + q * 4);
      a[0] += bv[0]; a[1] += bv[1]; a[2] += bv[2]; a[3] += bv[3];
      acc[t] = a;
    }
    float m = fmaxf(fmaxf(fabsf(a[0]), fabsf(a[1])), fmaxf(fabsf(a[2]), fabsf(a[3])));
    if (t < 4) mtop = fmaxf(mtop, m); else mbot = fmaxf(mbot, m);
  }
#pragma unroll
  for (int s = 1; s < 64; s <<= 1) {
    mtop = fmaxf(mtop, __shfl_xor(mtop, s, 64));
    mbot = fmaxf(mbot, __shfl_xor(mbot, s, 64));
  }
  if (lane == 0) {
    wmt[wave] = mtop;
    wmb[wave] = mbot;
  }
  __syncthreads();
  float bt = wmt[0], bb = wmb[0];
#pragma unroll
  for (int i = 1; i < 8; ++i) {
    bt = fmaxf(bt, wmt[i]);
    bb = fmaxf(bb, wmb[i]);
  }
  const float invt = 127.f / fmaxf(bt, 1e-20f);
  const float invb = 127.f / fmaxf(bb, 1e-20f);

  if (ok) {
    const int node = rowbase + l16;
#pragma unroll
    for (int t = 0; t < 8; ++t) {
      *(uint32*)(P8 + (size_t)node * 128 + t * 16 + q * 4) =
          pack4_i8(acc[t], (t < 4) ? invt : invb);
    }
  }
  if (tid == 0)
    Sc[blockIdx.x] = make_float2(bt * (1.f / 127.f), bb * (1.f / 127.f));
}

// ---- edge kernel: 2 random 64B gathers/edge + dequant dot + gumbel-sigmoid ----
// Block 256 = 4 waves; wave = 32 edges = 2 slots of 16 edges; 4 lanes/edge,
// 16B (dwordx4) per lane. Sc table staged in LDS (R5-proven).
// R12 tweak: SPECULATIVE round-1 loads. All of ei[2el], ei[2el+1], ei[el],
// ei[nm+el], u1[el], u2[el] are in-bounds under BOTH int32/int64 layouts
// (word index < 2*nm), so they issue concurrently; only the idx64 column
// word ei[2*(nm+el)] (conditionally OOB for int32) stays guarded and
// overlaps the row gathers. Dependent memory rounds: 4 -> 3, and the
// trailing u1/u2 epilogue round is eliminated (values redistributed via
// all-lanes-active shfl).
__global__ __launch_bounds__(256, 8) void edge_kernel(
    const uint8_t* __restrict__ P8, const float2* __restrict__ Sc,
    const int* __restrict__ ei,
    const float* __restrict__ u1, const float* __restrict__ u2,
    const float* __restrict__ W2, const float* __restrict__ b2,
    float* __restrict__ out, int num_edges, int nsc) {
  __shared__ float2 scs[2048];  // 16 KB: holds up to 2048 node-blocks
  const int tid = threadIdx.x;
  const bool useLds = (nsc <= 2048);
  if (useLds) {
    for (int i = tid; i < nsc; i += 256) scs[i] = Sc[i];
  }

  const int wave = tid >> 6;
  const int lane = tid & 63;
  const int g = lane >> 2;  // edge-within-slot (0..15)
  const int h = lane & 3;   // lane-within-edge (0..3)
  const int wbase = blockIdx.x * 128 + wave * 32;

  // W2 fragment: 16 floats per lane (hidden units h*16 .. h*16+15)
  f4v w0 = *(const f4v*)(W2 + h * 16);
  f4v w1v = *(const f4v*)(W2 + h * 16 + 4);
  f4v w2v = *(const f4v*)(W2 + h * 16 + 8);
  f4v w3v = *(const f4v*)(W2 + h * 16 + 12);
  const float bias2 = b2[0];

  int el = wbase + (lane & 31);
  if (el > num_edges - 1) el = num_edges - 1;

  // ---- round 1: all provably-in-bounds loads issued together
  int wlo = ei[2 * el];            // int64 row low word
  int whi = ei[2 * el + 1];        // int64 row high word (0 iff int64 layout)
  int a32 = ei[el];                // int32 row idx
  int b32 = ei[num_edges + el];    // int32 col idx
  float pre1 = u1[el];             // gumbel uniforms (redistributed later)
  float pre2 = u2[el];

  // int64-vs-int32 detection (per-wave uniform): int64 LE => odd words all 0
  unsigned long long oddmask = __ballot(whi != 0);
  const bool idx64 = (oddmask == 0ULL);
  const int eR = idx64 ? wlo : a32;

  __syncthreads();  // scs ready

  // ---- round 2: row gathers (eR known); idx64 column word loads concurrently
  uint4 ar[2], ac[2];
  float srv[2], scv[2];
  int eC;
  if (idx64) {
    eC = ei[2 * (num_edges + el)];  // guarded: only exists in int64 layout
  } else {
    eC = b32;
  }
#pragma unroll
  for (int s = 0; s < 2; ++s) {
    int nr = __shfl(eR, s * 16 + g, 64);
    ar[s] = *(const uint4*)(P8 + (size_t)nr * 128 + h * 16);
    srv[s] = useLds ? scs[nr >> 7].x : Sc[nr >> 7].x;
  }
  // redistribute prefetched uniforms to epilogue lanes (all lanes active)
  float a1v[2], a2v[2];
#pragma unroll
  for (int s = 0; s < 2; ++s) {
    a1v[s] = __shfl(pre1, s * 16 + g, 64);
    a2v[s] = __shfl(pre2, s * 16 + g, 64);
  }
  // ---- round 3: column gathers (eC known)
#pragma unroll
  for (int s = 0; s < 2; ++s) {
    int nc = __shfl(eC, s * 16 + g, 64);
    ac[s] = *(const uint4*)(P8 + (size_t)nc * 128 + 64 + h * 16);
    scv[s] = useLds ? scs[nc >> 7].y : Sc[nc >> 7].y;
  }

#pragma unroll
  for (int s = 0; s < 2; ++s) {
    float accv = 0.f;
    const float st = srv[s], sb = scv[s];
    const uint32 rw[4] = {ar[s].x, ar[s].y, ar[s].z, ar[s].w};
    const uint32 cw[4] = {ac[s].x, ac[s].y, ac[s].z, ac[s].w};
    const f4v wv[4] = {w0, w1v, w2v, w3v};
#pragma unroll
    for (int wi = 0; wi < 4; ++wi) {
#pragma unroll
      for (int j = 0; j < 4; ++j) {
        float hv = fmaxf(i8tof(rw[wi], j) * st + i8tof(cw[wi], j) * sb, 0.f);
        accv = fmaf(hv, wv[wi][j], accv);
      }
    }
    accv += __shfl_xor(accv, 1, 64);
    accv += __shfl_xor(accv, 2, 64);
    if (h == 0) {
      int e = wbase + s * 16 + g;
      if (e < num_edges) {
        float a1 = fminf(fmaxf(a1v[s], GS_EPS), 1.0f);
        float a2 = fminf(fmaxf(a2v[s], GS_EPS), 1.0f);
        float g1 = -__logf(-__logf(a1));
        float g2 = -__logf(-__logf(a2));
        float x = accv + bias2 + g1 - g2;  // TEMP = 1.0
        out[e] = 1.f / (1.f + __expf(-x));
      }
    }
  }
}

extern "C" void kernel_launch(void* const* d_in, const int* in_sizes, int n_in,
                              void* d_out, int out_size, void* d_ws, size_t ws_size,
                              hipStream_t stream) {
  const float* node_embed = (const float*)d_in[0];
  const int* ei = (const int*)d_in[1];
  const float* u1 = (const float*)d_in[2];
  const float* u2 = (const float*)d_in[3];
  const float* W1 = (const float*)d_in[4];
  const float* b1 = (const float*)d_in[5];
  const float* W2 = (const float*)d_in[6];
  const float* b2 = (const float*)d_in[7];
  float* out = (float*)d_out;

  const int num_edges = in_sizes[2];        // u1 length
  const int num_nodes = in_sizes[0] / 128;  // embed_dim = 128
  const int pblocks = (num_nodes + 127) / 128;

  // workspace layout (256B-aligned chunks)
  char* w = (char*)d_ws;
  uint8_t* P8 = (uint8_t*)w;   w += ((size_t)num_nodes * 128 + 255) & ~(size_t)255;
  float2* Sc = (float2*)w;

  pcompute_kernel<<<pblocks, 512, 0, stream>>>(node_embed, W1, b1, P8, Sc, num_nodes);
  const int eblocks = (num_edges + 127) / 128;
  edge_kernel<<<eblocks, 256, 0, stream>>>(P8, Sc, ei, u1, u2, W2, b2, out, num_edges, pblocks);
}